// Round 4
// baseline (746.539 us; speedup 1.0000x reference)
//
#include <hip/hip_runtime.h>

typedef float   f32x4 __attribute__((ext_vector_type(4)));
typedef _Float16 f16x8 __attribute__((ext_vector_type(8)));

#define DEV static __device__ __forceinline__

// ---- problem constants ----
#define BB 4
#define TT 32
#define DD 768
#define SS 256          // Hp*Wp
#define NHD 12
#define HD 64
#define NSEQ  (BB*SS)   // 1024 sequences
#define MTOK  (NSEQ*TT) // 32768 tokens

// ---------------------------------------------------------------------------
// K0: merged prep — transpose h, convert weights, u_pen. One launch, 3200
// blocks, fills the device instead of three serial tail-bound launches.
// ---------------------------------------------------------------------------
__global__ __launch_bounds__(256) void k_prep(const float* __restrict__ h,
                                              const float* __restrict__ u,
                                              const float* __restrict__ lam,
                                              const float* __restrict__ Wq,
                                              const float* __restrict__ Wk,
                                              const float* __restrict__ Wv,
                                              const float* __restrict__ Wo,
                                              _Float16* __restrict__ A,
                                              _Float16* __restrict__ WQKV,
                                              _Float16* __restrict__ WoH,
                                              float* __restrict__ upen) {
  __shared__ _Float16 Tl[256 * 65];
  const int blk = blockIdx.x;
  const int t = threadIdx.x;
  if (blk < 1536) {
    // ---- transpose h (B,T,D,Hp,Wp) fp32 -> A[token][d] f16 ----
    const int slab = blk & 127;
    const int d0   = (blk >> 7) * 64;
    const float4* hv = (const float4*)(h + (slab * DD + d0) * SS);
    #pragma unroll
    for (int i = 0; i < 16; ++i) {
      int dd = i * 4 + (t >> 6);
      int s4 = (t & 63) * 4;
      float4 v = hv[dd * 64 + (t & 63)];
      Tl[(s4 + 0) * 65 + dd] = (_Float16)v.x;
      Tl[(s4 + 1) * 65 + dd] = (_Float16)v.y;
      Tl[(s4 + 2) * 65 + dd] = (_Float16)v.z;
      Tl[(s4 + 3) * 65 + dd] = (_Float16)v.w;
    }
    __syncthreads();
    #pragma unroll
    for (int p = 0; p < 8; ++p) {
      int s  = p * 32 + (t >> 3);
      int dd = (t & 7) * 8;
      f16x8 val;
      #pragma unroll
      for (int j = 0; j < 8; ++j) val[j] = Tl[s * 65 + dd + j];
      *(f16x8*)(A + (slab * SS + s) * DD + d0 + dd) = val;
    }
  } else if (blk < 1536 + 1152) {
    // ---- weights fp32 -> f16 ----
    int idx = (blk - 1536) * 256 + t;
    int row = idx / 96;
    int c8  = (idx % 96) * 8;
    const float* src; _Float16* dst;
    if (row < 768)       { src = Wq + row * 768;          dst = WQKV + row * 768; }
    else if (row < 1536) { src = Wk + (row - 768) * 768;  dst = WQKV + row * 768; }
    else if (row < 2304) { src = Wv + (row - 1536) * 768; dst = WQKV + row * 768; }
    else                 { src = Wo + (row - 2304) * 768; dst = WoH  + (row - 2304) * 768; }
    float4 v0 = *(const float4*)(src + c8);
    float4 v1 = *(const float4*)(src + c8 + 4);
    f16x8 o;
    o[0]=(_Float16)v0.x; o[1]=(_Float16)v0.y; o[2]=(_Float16)v0.z; o[3]=(_Float16)v0.w;
    o[4]=(_Float16)v1.x; o[5]=(_Float16)v1.y; o[6]=(_Float16)v1.z; o[7]=(_Float16)v1.w;
    *(f16x8*)(dst + c8) = o;
  } else {
    // ---- u_pen[(b*256+s)*32 + t] = lam * mean_d u ----
    int ublk = blk - 2688;
    int slab = ublk >> 2;
    int q    = ublk & 3;
    int s    = t;
    const float* base = u + (slab * DD + q * 192) * SS + s;
    float sum = 0.f;
    for (int d = 0; d < 192; ++d) sum += base[d * SS];
    int b = slab >> 5, tt = slab & 31;
    float l = lam[slab * SS + s];
    atomicAdd(&upen[(b * SS + s) * TT + tt], sum * l * (1.0f / 768.0f));
  }
}

// ---------------------------------------------------------------------------
// K2: QKV GEMM, barrier-free register-tiled. 1 wave/block, 64m x 128n tile.
// A and WQKV are k-major -> MFMA fragments are contiguous 16B k-runs loaded
// DIRECTLY from global (each 64B line = one row's full BK=32 chunk: perfect
// sector efficiency, L2-resident). No LDS, no __syncthreads -> compiler emits
// fine-grained vmcnt(N), loads pipeline across iterations.
// Grid swizzle: xcd = mt&7; for fixed mt the 18 nt-blocks are 8 apart ->
// same XCD, temporally adjacent -> A-tile fetched from HBM once.
// ---------------------------------------------------------------------------
__global__ __launch_bounds__(64, 2) void k_gemm_qkv(const _Float16* __restrict__ A,
                                                    const _Float16* __restrict__ Bw,
                                                    const float* __restrict__ bq,
                                                    const float* __restrict__ bk,
                                                    const float* __restrict__ bv,
                                                    _Float16* __restrict__ Qp,
                                                    _Float16* __restrict__ Kp,
                                                    _Float16* __restrict__ Vp) {
  const int bidx = blockIdx.x;              // 9216 = 64 mtg * 18 nt * 8 mtl
  const int mtg = bidx / 144, rem = bidx % 144;
  const int nt = rem >> 3, mt = mtg * 8 + (rem & 7);
  const int m0 = mt * 64, n0 = nt * 128;
  const int lane = threadIdx.x;
  const int lr = lane & 15, lk = (lane >> 4) * 8;
  const _Float16* ap = A  + (long)(m0 + lr) * DD + lk;
  const _Float16* bp = Bw + (long)(n0 + lr) * DD + lk;
  f32x4 acc[4][8] = {};
  #pragma unroll
  for (int it = 0; it < 24; ++it) {
    const int ko = it * 32;
    f16x8 af[4], bf[8];
    #pragma unroll
    for (int mi = 0; mi < 4; ++mi) af[mi] = *(const f16x8*)(ap + mi * (16 * DD) + ko);
    #pragma unroll
    for (int ni = 0; ni < 8; ++ni) bf[ni] = *(const f16x8*)(bp + ni * (16 * DD) + ko);
    #pragma unroll
    for (int mi = 0; mi < 4; ++mi)
      #pragma unroll
      for (int ni = 0; ni < 8; ++ni)
        acc[mi][ni] = __builtin_amdgcn_mfma_f32_16x16x32_f16(af[mi], bf[ni], acc[mi][ni], 0, 0, 0);
  }
  // epilogue: packed per-(seq,head) output [seq][head][t][hd]; Q scaled 1/8
  const int sel = nt / 6;                                  // 0=Q 1=K 2=V
  const float scale = (sel == 0) ? 0.125f : 1.0f;
  const float* bias = (sel == 0) ? bq : ((sel == 1) ? bk : bv);
  _Float16* dst = (sel == 0) ? Qp : ((sel == 1) ? Kp : Vp);
  const int slab = mt >> 2, s0 = (mt & 3) * 64;
  const int bb = slab >> 5, tt = slab & 31;
  #pragma unroll
  for (int ni = 0; ni < 8; ++ni) {
    int n768 = n0 - sel * 768 + ni * 16 + lr;
    int head = n768 >> 6, hd = n768 & 63;
    float bsv = bias[n768];
    long hb = (long)head * 2048 + tt * 64 + hd;
    #pragma unroll
    for (int mi = 0; mi < 4; ++mi) {
      f32x4 v = acc[mi][ni];
      #pragma unroll
      for (int r = 0; r < 4; ++r) {
        int s = s0 + mi * 16 + (lane >> 4) * 4 + r;
        long seq = bb * 256 + s;
        dst[seq * 24576 + hb] = (_Float16)((v[r] + bsv) * scale);
      }
    }
  }
}

// ---------------------------------------------------------------------------
// K3: attention. 1 wave per (seq, head); dense 4KB Q/K/V blocks.
// V transposed through per-wave LDS (stride 66). O token-major into Abuf.
// ---------------------------------------------------------------------------
__global__ __launch_bounds__(256) void k_attn(const _Float16* __restrict__ Qp,
                                              const _Float16* __restrict__ Kp,
                                              const _Float16* __restrict__ Vp,
                                              const float* __restrict__ upen,
                                              _Float16* __restrict__ O) {
  __shared__ _Float16 lds[4][32 * 66 + 32 * 40];
  const int w = threadIdx.x >> 6, lane = threadIdx.x & 63;
  const int seq = blockIdx.x / 3, hg = blockIdx.x % 3;
  const int head = hg * 4 + w;
  const int b = seq >> 8, s = seq & 255;
  _Float16* Vs = &lds[w][0];
  _Float16* Ps = &lds[w][32 * 66];
  const long base = (long)(seq * NHD + head) * 2048;
  const _Float16* Qb = Qp + base;
  const _Float16* Kb = Kp + base;
  const _Float16* Vb = Vp + base;

  {
    int t = lane & 31, hh = (lane >> 5) * 32;
    f16x8 vc[4];
    #pragma unroll
    for (int c = 0; c < 4; ++c) vc[c] = *(const f16x8*)(Vb + t * 64 + hh + c * 8);
    #pragma unroll
    for (int c = 0; c < 4; ++c)
      #pragma unroll
      for (int p = 0; p < 4; ++p) {
        union { _Float16 h[2]; unsigned u; } pk;
        pk.h[0] = vc[c][2 * p]; pk.h[1] = vc[c][2 * p + 1];
        *(unsigned*)&Vs[t * 66 + hh + c * 8 + 2 * p] = pk.u;
      }
  }
  f16x8 qf[2][2], kf[2][2];
  #pragma unroll
  for (int i = 0; i < 2; ++i)
    #pragma unroll
    for (int ks = 0; ks < 2; ++ks) {
      int off = (i * 16 + (lane & 15)) * 64 + ks * 32 + (lane >> 4) * 8;
      qf[i][ks] = *(const f16x8*)(Qb + off);
      kf[i][ks] = *(const f16x8*)(Kb + off);
    }
  f32x4 sc[2][2] = {};
  #pragma unroll
  for (int mq = 0; mq < 2; ++mq)
    #pragma unroll
    for (int nk = 0; nk < 2; ++nk)
      #pragma unroll
      for (int ks = 0; ks < 2; ++ks)
        sc[mq][nk] = __builtin_amdgcn_mfma_f32_16x16x32_f16(qf[mq][ks], kf[nk][ks], sc[mq][nk], 0, 0, 0);

  const float up0 = upen[seq * TT + (lane & 15)];
  const float up1 = upen[seq * TT + 16 + (lane & 15)];

  #pragma unroll
  for (int mq = 0; mq < 2; ++mq) {
    #pragma unroll
    for (int r = 0; r < 4; ++r) {
      float s0 = sc[mq][0][r] - up0;
      float s1 = sc[mq][1][r] - up1;
      float mx = fmaxf(s0, s1);
      #pragma unroll
      for (int off = 1; off < 16; off <<= 1) mx = fmaxf(mx, __shfl_xor(mx, off, 64));
      float e0 = __expf(s0 - mx), e1 = __expf(s1 - mx);
      float sum = e0 + e1;
      #pragma unroll
      for (int off = 1; off < 16; off <<= 1) sum += __shfl_xor(sum, off, 64);
      float inv = 1.0f / sum;
      int row = mq * 16 + (lane >> 4) * 4 + r;
      Ps[row * 40 + (lane & 15)]      = (_Float16)(e0 * inv);
      Ps[row * 40 + 16 + (lane & 15)] = (_Float16)(e1 * inv);
    }
  }
  f16x8 pf[2];
  #pragma unroll
  for (int mq = 0; mq < 2; ++mq)
    pf[mq] = *(const f16x8*)(Ps + (mq * 16 + (lane & 15)) * 40 + (lane >> 4) * 8);
  f32x4 oacc[2][4] = {};
  #pragma unroll
  for (int nh = 0; nh < 4; ++nh) {
    int hd = nh * 16 + (lane & 15);
    f16x8 vf;
    #pragma unroll
    for (int j = 0; j < 8; ++j) vf[j] = Vs[((lane >> 4) * 8 + j) * 66 + hd];
    #pragma unroll
    for (int mq = 0; mq < 2; ++mq)
      oacc[mq][nh] = __builtin_amdgcn_mfma_f32_16x16x32_f16(pf[mq], vf, oacc[mq][nh], 0, 0, 0);
  }
  #pragma unroll
  for (int mq = 0; mq < 2; ++mq)
    #pragma unroll
    for (int nh = 0; nh < 4; ++nh) {
      int hd = nh * 16 + (lane & 15);
      #pragma unroll
      for (int r = 0; r < 4; ++r) {
        int t = mq * 16 + (lane >> 4) * 4 + r;
        O[((long)((b << 5) + t) * SS + s) * DD + head * HD + hd] = (_Float16)oacc[mq][nh][r];
      }
    }
}

// ---------------------------------------------------------------------------
// K4: output GEMM, barrier-free register-tiled, swapped operands:
// C'[R][token] = Wo[R][:] . O[token][:] + bo[R]. 1 wave/block, 64R x 128tok.
// Grid swizzle: xcd = ct&7; the 12 R-tiles of one token-tile are 8 apart ->
// same XCD, temporally adjacent -> O-tile L2-hot across all R-tiles.
// Final store is s-contiguous fp32 (coalesced 64B runs).
// ---------------------------------------------------------------------------
__global__ __launch_bounds__(64, 2) void k_gemm_out(const _Float16* __restrict__ Wn,
                                                    const _Float16* __restrict__ O,
                                                    const float* __restrict__ bo,
                                                    float* __restrict__ out) {
  const int bidx = blockIdx.x;              // 3072 = 32 ctg * 12 rt * 8 ctl
  const int ctg = bidx / 96, rem = bidx % 96;
  const int rt = rem >> 3, ct = ctg * 8 + (rem & 7);
  const int R0 = rt * 64, C0 = ct * 128;
  const int lane = threadIdx.x;
  const int lr = lane & 15, lk = (lane >> 4) * 8;
  const _Float16* ap = Wn + (long)(R0 + lr) * DD + lk;
  const _Float16* bp = O  + (long)(C0 + lr) * DD + lk;
  f32x4 acc[4][8] = {};
  #pragma unroll
  for (int it = 0; it < 24; ++it) {
    const int ko = it * 32;
    f16x8 af[4], bf[8];
    #pragma unroll
    for (int ri = 0; ri < 4; ++ri) af[ri] = *(const f16x8*)(ap + ri * (16 * DD) + ko);
    #pragma unroll
    for (int ci = 0; ci < 8; ++ci) bf[ci] = *(const f16x8*)(bp + ci * (16 * DD) + ko);
    #pragma unroll
    for (int ri = 0; ri < 4; ++ri)
      #pragma unroll
      for (int ci = 0; ci < 8; ++ci)
        acc[ri][ci] = __builtin_amdgcn_mfma_f32_16x16x32_f16(af[ri], bf[ci], acc[ri][ci], 0, 0, 0);
  }
  const int slab = C0 >> 8, sbase = C0 & 255;
  #pragma unroll
  for (int ri = 0; ri < 4; ++ri) {
    #pragma unroll
    for (int ci = 0; ci < 8; ++ci) {
      int s = sbase + ci * 16 + lr;
      f32x4 v = acc[ri][ci];
      #pragma unroll
      for (int r = 0; r < 4; ++r) {
        int R = R0 + ri * 16 + (lane >> 4) * 4 + r;
        out[((long)slab * DD + R) * SS + s] = v[r] + bo[R];
      }
    }
  }
}

// ---------------------------------------------------------------------------
// host launcher.  ws layout (~206 MiB):
//   [0)          A f16 [32768][768]  (reused as O after attention)
//   [50331648)   WQKV f16 [2304][768]
//   [53870592)   Wo   f16 [768][768]
//   [55050240)   upen f32 [32768]
//   [55181312)   Qp f16 [1024][12][32][64]
//   [105512960)  Kp f16
//   [155844608)  Vp f16   end 206176256
// ---------------------------------------------------------------------------
extern "C" void kernel_launch(void* const* d_in, const int* in_sizes, int n_in,
                              void* d_out, int out_size, void* d_ws, size_t ws_size,
                              hipStream_t stream) {
  const float* h   = (const float*)d_in[0];
  const float* u   = (const float*)d_in[1];
  const float* lam = (const float*)d_in[2];
  const float* Wq  = (const float*)d_in[3];
  const float* bq  = (const float*)d_in[4];
  const float* Wk  = (const float*)d_in[5];
  const float* bk  = (const float*)d_in[6];
  const float* Wv  = (const float*)d_in[7];
  const float* bv  = (const float*)d_in[8];
  const float* Wo  = (const float*)d_in[9];
  const float* bo  = (const float*)d_in[10];
  float* out = (float*)d_out;

  char* ws = (char*)d_ws;
  _Float16* Abuf = (_Float16*)(ws);
  _Float16* WQKV = (_Float16*)(ws + 50331648);
  _Float16* WoH  = (_Float16*)(ws + 53870592);
  float*    upen = (float*)   (ws + 55050240);
  _Float16* Qp   = (_Float16*)(ws + 55181312);
  _Float16* Kp   = (_Float16*)(ws + 105512960);
  _Float16* Vp   = (_Float16*)(ws + 155844608);

  hipMemsetAsync(upen, 0, 32768 * sizeof(float), stream);
  k_prep<<<3200, 256, 0, stream>>>(h, u, lam, Wq, Wk, Wv, Wo, Abuf, WQKV, WoH, upen);
  k_gemm_qkv<<<9216, 64, 0, stream>>>(Abuf, WQKV, bq, bk, bv, Qp, Kp, Vp);
  k_attn<<<1024 * 3, 256, 0, stream>>>(Qp, Kp, Vp, upen, Abuf);
  k_gemm_out<<<3072, 64, 0, stream>>>(WoH, Abuf, bo, out);
}